// Round 5
// baseline (203.991 us; speedup 1.0000x reference)
//
#include <hip/hip_runtime.h>
#include <math.h>

#define NVIEW 8
#define CIN   32
#define HF    128
#define WF    128
#define C1    32
#define C2    16
#define C3    8
#define RESO  64
#define PLANE (HF*WF)          // 16384 texels per (v,group) plane, uint4 units

typedef _Float16 half8_t  __attribute__((ext_vector_type(8)));
typedef _Float16 half2_t  __attribute__((ext_vector_type(2)));
typedef float    floatx4  __attribute__((ext_vector_type(4)));

static __device__ __forceinline__ float vox_coord(int idx, float b) {
    const float VOXEL = (float)(0.3 / 64.0);
    const float HALFV = (float)(0.3 / 128.0);
    return (float)idx * VOXEL + HALFV + b;
}

// ---- K1: G in fp16, planar 8-channel groups: Gh[(v*4+grp)*PLANE + pix] = 16 B
// (8 halves, RTNE). SINGLE-PASS: each thread owns one texel and computes all
// 32 layer-1 outputs (feats read once; it is L3-resident anyway).
// Per-output FMA order over c is unchanged -> bit-identical to prior rounds.
// Block 512 preps mats / fp16 weight frags. ----
__global__ void __launch_bounds__(256) k_g(const float* __restrict__ feats,
                                           const float* __restrict__ W1,
                                           const float* __restrict__ b1,
                                           uint4* __restrict__ Gh,
                                           const float* __restrict__ Ks,
                                           const float* __restrict__ poses,
                                           const int* __restrict__ ihp,
                                           const int* __restrict__ iwp,
                                           const float* __restrict__ W2,
                                           const float* __restrict__ b2,
                                           const float* __restrict__ W3,
                                           const float* __restrict__ b3,
                                           float* __restrict__ mats,
                                           _Float16* __restrict__ w2f,
                                           _Float16* __restrict__ w3f,
                                           float* __restrict__ b2f,
                                           float* __restrict__ b3f) {
    if (blockIdx.x == 512) {
        int t = threadIdx.x;
        if (t < NVIEW * 12) {
            int v = t / 12, rc = t % 12, r = rc / 4, c = rc % 4;
            const float* K = Ks + v * 9;
            const float* P = poses + v * 12;
            float s = K[r*3+0]*P[0*4+c] + K[r*3+1]*P[1*4+c] + K[r*3+2]*P[2*4+c];
            float sc = (r == 0) ? 63.5f / (float)iwp[0]
                     : (r == 1) ? 63.5f / (float)ihp[0] : 1.0f;
            mats[v*12 + r*4 + c] = s * sc;
        }
        if (t < 64) {
            int n = t & 15, g = t >> 4;
            // B-frag for mfma_f32_16x16x32_f16: lane holds B[k=8g+j][n], j=0..7
#pragma unroll
            for (int jj = 0; jj < 8; jj++) {
                int kk = 8 * g + jj;
                w2f[t*8 + jj] = (_Float16)W2[kk * C2 + n];
                float w3v = (kk < C2 && n < C3) ? W3[kk * C3 + n] : 0.0f;  // K,N zero-pad
                w3f[t*8 + jj] = (_Float16)w3v;
            }
            b2f[t] = b2[n];
            b3f[t] = (n < C3) ? b3[n] : 0.0f;
        }
        return;
    }
    // 512 blocks: [view(8)][pixblk(64)] ; thread = one texel, all 32 outputs
    int bx = blockIdx.x;
    int pix = (bx & 63) * 256 + threadIdx.x;   // coalesced
    int v   = bx >> 6;
    const float* fp = feats + ((size_t)v * CIN) * PLANE + pix;
    float g[32];
#pragma unroll
    for (int o = 0; o < C1; o++) g[o] = b1[o];
#pragma unroll
    for (int cc = 0; cc < CIN; cc += 8) {
        float fc[8];
#pragma unroll
        for (int q = 0; q < 8; q++) fc[q] = fp[(size_t)(cc + q) * PLANE];
#pragma unroll
        for (int q = 0; q < 8; q++) {
#pragma unroll
            for (int o = 0; o < C1; o++)
                g[o] = fmaf(fc[q], W1[(cc + q) * C1 + o], g[o]);
        }
    }
#pragma unroll
    for (int grp = 0; grp < 4; grp++) {
        union { half2_t h2[4]; uint4 u; } pk;
#pragma unroll
        for (int q = 0; q < 4; q++) {
            half2_t p = { (_Float16)g[grp*8 + 2*q], (_Float16)g[grp*8 + 2*q + 1] };   // RTNE
            pk.h2[q] = p;
        }
        Gh[((size_t)(v * 4 + grp)) * PLANE + pix] = pk.u;
    }
}

// ---- K2: HALF-COLUMN waves for 8 waves/SIMD occupancy.
// R2 evidence: k_main is VALU/latency bound at VGPR-capped occupancy
// (VALUBusy 48% @ 2 waves/SIMD, MfmaUtil 3%, HBM ~0). Occupancy steps at
// VGPR=64/128 — the only remaining lever is <=64 VGPR -> 8 waves/SIMD.
// Wave = 32 points (half an x-column) x 8 views: accumulators 48->24 VGPR,
// 2 MFMA tiles/view instead of 4. Block = 4 waves = 2 columns x 2 halves,
// grid 2048. The per-view mask sum (popc over the FULL 64-pt column) is
// exchanged between partner waves via double-buffered LDS + one
// __syncthreads per view (subsumes the old lgkm drains). msr uses the
// summed popcounts (integer add) -> bit-identical output. ----
__global__ void __launch_bounds__(256, 8) k_main(
    const uint4* __restrict__ Gh,
    const float* __restrict__ mats, const float* __restrict__ bbox,
    const _Float16* __restrict__ w2f, const _Float16* __restrict__ w3f,
    const float* __restrict__ b2f, const float* __restrict__ b3f,
    float* __restrict__ out) {
#pragma clang fp contract(fast)
    __shared__ __align__(16) _Float16 h2s[4][32 * 24];   // per-wave [point][ch] slice
    __shared__ int pops[2][4];                           // per-view popc, dbuf by parity

    int tid  = threadIdx.x;
    int wv   = tid >> 6;                   // 0..3: (colInBlock<<1)|half
    int lane = tid & 63;
    int bxs  = (blockIdx.x & 7) * 256 + (blockIdx.x >> 3);  // XCD swizzle (2048 = 8*256)
    int col  = bxs * 2 + (wv >> 1);        // 4096 columns: (k<<6)|j
    int h    = wv & 1;                     // half: points h*32 .. h*32+31
    int j  = col & 63;
    int kz = col >> 6;
    _Float16* h2b = h2s[wv];

    int m = lane & 15, g = lane >> 4;
    float y = vox_coord(j, bbox[1]);
    float z = vox_coord(kz, bbox[2]);
    float b0 = bbox[0];

    half8_t w2frag = *(const half8_t*)(w2f + lane * 8);
    half8_t w3frag = *(const half8_t*)(w3f + lane * 8);
    float b2c = b2f[lane];
    float b3c = b3f[lane];
    floatx4 cb2 = {b2c, b2c, b2c, b2c};
    floatx4 cb3 = {b3c, b3c, b3c, b3c};
    const half2_t z2 = { (_Float16)0.0f, (_Float16)0.0f };

    float M1[8], Msq[8], S16[8];
#pragma unroll
    for (int c = 0; c < 8; c++) { M1[c] = 0.0f; Msq[c] = 0.0f; S16[c] = 0.0f; }

#pragma unroll 1
    for (int v = 0; v < NVIEW; v++) {
        const float* M = mats + v * 12;
        const uint4* Gv = Gh + (size_t)(v * 4 + g) * PLANE;   // my 8-ch plane group

        // column constants: u = M0*x + Ku  (same association as reference:
        // M0*x + (M1*y + (M2*z + M3)) -> bit-identical to previous rounds)
        float Ku = fmaf(M[1], y, fmaf(M[2],  z, M[3]));
        float Kv = fmaf(M[5], y, fmaf(M[6],  z, M[7]));
        float Kz = fmaf(M[9], y, fmaf(M[10], z, M[11]));
        float M0 = M[0], M4 = M[4], M8 = M[8];

        floatx4 c2v[2];
        unsigned int ballo[2];
        int popc = 0;

#pragma unroll
        for (int T = 0; T < 2; T++) {
            int ipt = h * 32 + T * 16 + m;             // point index in column
            float x = vox_coord(ipt, b0);
            float u  = fmaf(M0, x, Ku);
            float vv = fmaf(M4, x, Kv);
            float zc = fmaf(M8, x, Kz);
            float invz = __builtin_amdgcn_rcpf(zc);
            float ix = u * invz;
            float iy = vv * invz;

            float fx0 = floorf(ix), fy0 = floorf(iy);
            float fx1 = fx0 + 1.0f, fy1 = fy0 + 1.0f;
            bool inb = (ix >= 0.0f) && (ix <= (float)(WF-1)) &&
                       (iy >= 0.0f) && (iy <= (float)(HF-1)) && (zc > 0.0f);
            int cx0 = (int)fminf(fmaxf(fx0, 0.0f), (float)(WF-1));
            int cx1 = (int)fminf(fmaxf(fx1, 0.0f), (float)(WF-1));
            int cy0 = (int)fminf(fmaxf(fy0, 0.0f), (float)(HF-1));
            int cy1 = (int)fminf(fmaxf(fy1, 0.0f), (float)(HF-1));
            float wnw = (fx1 - ix) * (fy1 - iy);
            float wne = (ix - fx0) * (fy1 - iy);
            float wsw = (fx1 - ix) * (iy - fy0);
            float wse = (ix - fx0) * (iy - fy0);

            unsigned long long bal = __ballot(inb);    // 4 identical copies per point
            ballo[T] = (unsigned int)bal;              // bits 0..15 = g-group 0
            popc += __popcll(bal);

            int t00 = cy0 * WF + cx0, t01 = cy0 * WF + cx1;
            int t10 = cy1 * WF + cx0, t11 = cy1 * WF + cx1;
            uint4 A = Gv[t00], B = Gv[t01], C = Gv[t10], D = Gv[t11];

            half2_t wnw2 = { (_Float16)wnw, (_Float16)wnw };   // RTNE
            half2_t wne2 = { (_Float16)wne, (_Float16)wne };
            half2_t wsw2 = { (_Float16)wsw, (_Float16)wsw };
            half2_t wse2 = { (_Float16)wse, (_Float16)wse };

            union { uint4 u; half2_t hh[4]; } ua, ub, uc, ud;
            ua.u = A; ub.u = B; uc.u = C; ud.u = D;
            union { half2_t h2[4]; half8_t h8; } r;
#pragma unroll
            for (int c = 0; c < 4; c++) {
                half2_t e = ua.hh[c]*wnw2 + ub.hh[c]*wne2 + uc.hh[c]*wsw2 + ud.hh[c]*wse2;
                r.h2[c] = __builtin_elementwise_max(e, z2);    // relu, packed
            }

            c2v[T] = __builtin_amdgcn_mfma_f32_16x16x32_f16(r.h8, w2frag, cb2, 0, 0, 0);
        }

        // publish half-column popc, stage h2 (wave-private slice; DS in-order
        // per wave so no extra drain needed — the barrier covers everything)
        if (lane == 0) pops[v & 1][wv] = popc;
#pragma unroll
        for (int T = 0; T < 2; T++) {
#pragma unroll
            for (int r = 0; r < 4; r++) {
                float vv = fmaxf(c2v[T][r], 0.0f);
                h2b[(T*16 + g*4 + r) * 24 + m] = (_Float16)vv;
            }
        }
        __syncthreads();

        // mask-sum over the FULL column = own + partner half (integer add ->
        // msr bit-identical to the monolithic-column version)
        int ptot = popc + pops[v & 1][wv ^ 1];
        float msr = __builtin_amdgcn_rcpf((float)(ptot >> 2) + 1e-8f);

        // layer 3: A = h2 rows (lane&15 = point-row), B = zero-padded W3, C = bias
#pragma unroll
        for (int T = 0; T < 2; T++) {
            half8_t a3 = *(const half8_t*)(h2b + (T*16 + m) * 24 + (g & 1) * 8);
            floatx4 c3 = __builtin_amdgcn_mfma_f32_16x16x32_f16(a3, w3frag, cb3, 0, 0, 0);
#pragma unroll
            for (int r = 0; r < 4; r++) {
                float w = ((ballo[T] >> (g*4 + r)) & 1u) ? msr : 0.0f;
                float val = c3[r];
                float t1 = w * val;
                S16[T*4+r] += w;
                M1[T*4+r]  += t1;
                Msq[T*4+r]  = fmaf(t1, val, Msq[T*4+r]);
            }
        }
    }

    // epilogue: lane (m<8, g) stores points h*32 + T*16 + g*4..+3,
    // mean plane m, var plane m+8
    if (m < C3) {
        size_t base = (size_t)col * 64 + h * 32;
#pragma unroll
        for (int T = 0; T < 2; T++) {
            float4 mn, vr;
            mn.x = M1[T*4+0]; mn.y = M1[T*4+1]; mn.z = M1[T*4+2]; mn.w = M1[T*4+3];
            vr.x = fmaf(mn.x*mn.x, S16[T*4+0]-2.0f, Msq[T*4+0]);
            vr.y = fmaf(mn.y*mn.y, S16[T*4+1]-2.0f, Msq[T*4+1]);
            vr.z = fmaf(mn.z*mn.z, S16[T*4+2]-2.0f, Msq[T*4+2]);
            vr.w = fmaf(mn.w*mn.w, S16[T*4+3]-2.0f, Msq[T*4+3]);
            size_t ob = base + T*16 + g*4;
            *(float4*)(out + (size_t)m       * 262144 + ob) = mn;
            *(float4*)(out + (size_t)(m + 8) * 262144 + ob) = vr;
        }
    }
}

// ---- launch ----
extern "C" void kernel_launch(void* const* d_in, const int* in_sizes, int n_in,
                              void* d_out, int out_size, void* d_ws, size_t ws_size,
                              hipStream_t stream) {
    const float* feats = (const float*)d_in[0];
    const float* poses = (const float*)d_in[1];
    const float* Ks    = (const float*)d_in[2];
    const float* bbox  = (const float*)d_in[3];
    const int*   img_h = (const int*)d_in[4];
    const int*   img_w = (const int*)d_in[5];
    const float* W1    = (const float*)d_in[6];
    const float* b1    = (const float*)d_in[7];
    const float* W2    = (const float*)d_in[8];
    const float* b2    = (const float*)d_in[9];
    const float* W3    = (const float*)d_in[10];
    const float* b3    = (const float*)d_in[11];
    float* out = (float*)d_out;
    float* ws  = (float*)d_ws;

    float*     mats = ws;                        // 96 floats (pad to 128)
    _Float16*  w2f  = (_Float16*)(ws + 128);     // 512 halves (256 floats)
    _Float16*  w3f  = (_Float16*)(ws + 384);     // 512 halves
    float*     b2f  = ws + 640;                  // 64
    float*     b3f  = ws + 704;                  // 64
    uint4*     Gh   = (uint4*)(ws + 768);        // 8*4*16384 uint4 = 8.39 MB, 16B-aligned

    hipLaunchKernelGGL(k_g, dim3(513), dim3(256), 0, stream,
                       feats, W1, b1, Gh, Ks, poses, img_h, img_w,
                       W2, b2, W3, b3, mats, w2f, w3f, b2f, b3f);
    hipLaunchKernelGGL(k_main, dim3(2048), dim3(256), 0, stream,
                       Gh, mats, bbox, w2f, w3f, b2f, b3f, out);
}

// Round 6
// 128.441 us; speedup vs baseline: 1.5882x; 1.5882x over previous
//
#include <hip/hip_runtime.h>
#include <math.h>

#define NVIEW 8
#define CIN   32
#define HF    128
#define WF    128
#define C1    32
#define C2    16
#define C3    8
#define RESO  64
#define PLANE (HF*WF)          // 16384 texels; Gh interleaved: 4 uint4 (32ch) per texel

typedef _Float16 half8_t  __attribute__((ext_vector_type(8)));
typedef _Float16 half2_t  __attribute__((ext_vector_type(2)));
typedef float    floatx4  __attribute__((ext_vector_type(4)));

static __device__ __forceinline__ float vox_coord(int idx, float b) {
    const float VOXEL = (float)(0.3 / 64.0);
    const float HALFV = (float)(0.3 / 128.0);
    return (float)idx * VOXEL + HALFV + b;
}

// wave-level LDS sync: each wave uses a private LDS slice; DS ops are in-order
// per wave, so only a lgkmcnt drain + compiler barrier is needed. No s_barrier.
static __device__ __forceinline__ void wave_lds_sync() {
    asm volatile("s_waitcnt lgkmcnt(0)" ::: "memory");
}

// ---- K1: G in fp16, INTERLEAVED layout: Gh[(v*PLANE + pix)*4 + grp] -> one
// 64 B cache line holds all 32 channels of a texel (gathers in k_main touch
// exactly one line per corner). Each thread owns one texel, computes all 32
// layer-1 outputs (per-output FMA order over c unchanged -> bit-identical).
// Block 512 preps mats / fp16 weight frags. ----
__global__ void __launch_bounds__(256) k_g(const float* __restrict__ feats,
                                           const float* __restrict__ W1,
                                           const float* __restrict__ b1,
                                           uint4* __restrict__ Gh,
                                           const float* __restrict__ Ks,
                                           const float* __restrict__ poses,
                                           const int* __restrict__ ihp,
                                           const int* __restrict__ iwp,
                                           const float* __restrict__ W2,
                                           const float* __restrict__ b2,
                                           const float* __restrict__ W3,
                                           const float* __restrict__ b3,
                                           float* __restrict__ mats,
                                           _Float16* __restrict__ w2f,
                                           _Float16* __restrict__ w3f,
                                           float* __restrict__ b2f,
                                           float* __restrict__ b3f) {
    if (blockIdx.x == 512) {
        int t = threadIdx.x;
        if (t < NVIEW * 12) {
            int v = t / 12, rc = t % 12, r = rc / 4, c = rc % 4;
            const float* K = Ks + v * 9;
            const float* P = poses + v * 12;
            float s = K[r*3+0]*P[0*4+c] + K[r*3+1]*P[1*4+c] + K[r*3+2]*P[2*4+c];
            float sc = (r == 0) ? 63.5f / (float)iwp[0]
                     : (r == 1) ? 63.5f / (float)ihp[0] : 1.0f;
            mats[v*12 + r*4 + c] = s * sc;
        }
        if (t < 64) {
            int n = t & 15, g = t >> 4;
            // B-frag for mfma_f32_16x16x32_f16: lane holds B[k=8g+j][n], j=0..7
#pragma unroll
            for (int jj = 0; jj < 8; jj++) {
                int kk = 8 * g + jj;
                w2f[t*8 + jj] = (_Float16)W2[kk * C2 + n];
                float w3v = (kk < C2 && n < C3) ? W3[kk * C3 + n] : 0.0f;  // K,N zero-pad
                w3f[t*8 + jj] = (_Float16)w3v;
            }
            b2f[t] = b2[n];
            b3f[t] = (n < C3) ? b3[n] : 0.0f;
        }
        return;
    }
    // 512 blocks: [view(8)][pixblk(64)] ; thread = one texel, all 32 outputs
    int bx = blockIdx.x;
    int pix = (bx & 63) * 256 + threadIdx.x;   // coalesced
    int v   = bx >> 6;
    const float* fp = feats + ((size_t)v * CIN) * PLANE + pix;
    float g[32];
#pragma unroll
    for (int o = 0; o < C1; o++) g[o] = b1[o];
#pragma unroll
    for (int cc = 0; cc < CIN; cc += 8) {
        float fc[8];
#pragma unroll
        for (int q = 0; q < 8; q++) fc[q] = fp[(size_t)(cc + q) * PLANE];
#pragma unroll
        for (int q = 0; q < 8; q++) {
#pragma unroll
            for (int o = 0; o < C1; o++)
                g[o] = fmaf(fc[q], W1[(cc + q) * C1 + o], g[o]);
        }
    }
    uint4* gp = Gh + ((size_t)v * PLANE + pix) * 4;
#pragma unroll
    for (int grp = 0; grp < 4; grp++) {
        union { half2_t h2[4]; uint4 u; } pk;
#pragma unroll
        for (int q = 0; q < 4; q++) {
            half2_t p = { (_Float16)g[grp*8 + 2*q], (_Float16)g[grp*8 + 2*q + 1] };   // RTNE
            pk.h2[q] = p;
        }
        gp[grp] = pk.u;
    }
}

// ---- K2: wave = one 64-voxel column, LANE = POINT.
// R4 computed every projection 4x (four 16-lane channel groups, same 16
// points). Here each lane projects its OWN point once (-30% VALU), gathers
// one 64B line per corner (interleaved Gh), blends all 32 channels with the
// SAME per-channel fp16 op order as before (mul,fma,fma,fma,max -> bit-
// identical), then redistributes MFMA A-frags through an XOR-swizzled LDS
// stage (write: lane p block q at slot q^((p>>1)&3); read: lane (m,g) slot
// g^((m>>1)&3) -> exactly 8 lanes per bank-group both ways = conflict-free).
// One 64-bit ballot/view (popc == old popc>>2). MFMA tiles, layer-3, and all
// accumulation arithmetic identical to R4. 4 waves/SIMD (proven no-spill
// regime; R5's (256,8) spilled to scratch and regressed 2x). ----
__global__ void __launch_bounds__(256, 4) k_main(
    const uint4* __restrict__ Gh,
    const float* __restrict__ mats, const float* __restrict__ bbox,
    const _Float16* __restrict__ w2f, const _Float16* __restrict__ w3f,
    const float* __restrict__ b2f, const float* __restrict__ b3f,
    float* __restrict__ out) {
#pragma clang fp contract(fast)
    __shared__ __align__(16) _Float16 a2s[4][64 * 32];   // per-wave A-stage (4 KB)
    __shared__ __align__(16) _Float16 h2s[4][64 * 24];   // per-wave h2 slice (3 KB)

    int tid  = threadIdx.x;
    int wv   = tid >> 6;
    int lane = tid & 63;
    int bxs  = (blockIdx.x & 7) * 128 + (blockIdx.x >> 3);  // XCD swizzle (bijective)
    int col  = bxs * 4 + wv;               // 4096 columns: (k<<6)|j
    int j  = col & 63;
    int kz = col >> 6;
    _Float16* a2b = a2s[wv];
    _Float16* h2b = h2s[wv];

    int m = lane & 15, g = lane >> 4;
    float y = vox_coord(j, bbox[1]);
    float z = vox_coord(kz, bbox[2]);
    float x = vox_coord(lane, bbox[0]);    // lane = point index in column

    half8_t w2frag = *(const half8_t*)(w2f + lane * 8);
    half8_t w3frag = *(const half8_t*)(w3f + lane * 8);
    float b2c = b2f[lane];
    float b3c = b3f[lane];
    floatx4 cb2 = {b2c, b2c, b2c, b2c};
    floatx4 cb3 = {b3c, b3c, b3c, b3c};
    const half2_t z2 = { (_Float16)0.0f, (_Float16)0.0f };

    // A-stage slot offsets (halves): write lane p block q -> p*32 + (q^((p>>1)&3))*8
    int wsw0 = (lane >> 1) & 3;            // write-side swizzle key
    int rsw0 = (m >> 1) & 3;               // read-side swizzle key (same key, p=T*16+m)

    float M1[16], Msq[16], S16[16];
#pragma unroll
    for (int c = 0; c < 16; c++) { M1[c] = 0.0f; Msq[c] = 0.0f; S16[c] = 0.0f; }

#pragma unroll 1
    for (int v = 0; v < NVIEW; v++) {
        const float* M = mats + v * 12;
        const uint4* Gp = Gh + (size_t)v * (PLANE * 4);

        // same association as reference: M0*x + (M1*y + (M2*z + M3))
        float Ku = fmaf(M[1], y, fmaf(M[2],  z, M[3]));
        float Kv = fmaf(M[5], y, fmaf(M[6],  z, M[7]));
        float Kz = fmaf(M[9], y, fmaf(M[10], z, M[11]));

        float u  = fmaf(M[0], x, Ku);
        float vv = fmaf(M[4], x, Kv);
        float zc = fmaf(M[8], x, Kz);
        float invz = __builtin_amdgcn_rcpf(zc);
        float ix = u * invz;
        float iy = vv * invz;

        float fx0 = floorf(ix), fy0 = floorf(iy);
        float fx1 = fx0 + 1.0f, fy1 = fy0 + 1.0f;
        bool inb = (ix >= 0.0f) && (ix <= (float)(WF-1)) &&
                   (iy >= 0.0f) && (iy <= (float)(HF-1)) && (zc > 0.0f);
        int cx0 = (int)fminf(fmaxf(fx0, 0.0f), (float)(WF-1));
        int cx1 = (int)fminf(fmaxf(fx1, 0.0f), (float)(WF-1));
        int cy0 = (int)fminf(fmaxf(fy0, 0.0f), (float)(HF-1));
        int cy1 = (int)fminf(fmaxf(fy1, 0.0f), (float)(HF-1));
        float wnw = (fx1 - ix) * (fy1 - iy);
        float wne = (ix - fx0) * (fy1 - iy);
        float wsw = (fx1 - ix) * (iy - fy0);
        float wse = (ix - fx0) * (iy - fy0);

        unsigned long long bal = __ballot(inb);    // bit p = point p in-bounds
        int popc = __popcll(bal);                  // true count (== old popc>>2)

        int t00 = cy0 * WF + cx0, t01 = cy0 * WF + cx1;
        int t10 = cy1 * WF + cx0, t11 = cy1 * WF + cx1;
        const uint4* pA = Gp + (size_t)t00 * 4;
        const uint4* pB = Gp + (size_t)t01 * 4;
        const uint4* pC = Gp + (size_t)t10 * 4;
        const uint4* pD = Gp + (size_t)t11 * 4;

        half2_t wnw2 = { (_Float16)wnw, (_Float16)wnw };   // RTNE, once per view
        half2_t wne2 = { (_Float16)wne, (_Float16)wne };
        half2_t wsw2 = { (_Float16)wsw, (_Float16)wsw };
        half2_t wse2 = { (_Float16)wse, (_Float16)wse };

        // blend all 32 channels: acc = A*wnw; fma B,C,D; relu.
        // per-channel op order identical to previous rounds -> bit-identical.
        union { uint4 u[4]; half2_t h[16]; } ca, cb, cc4, cd, acc;
#pragma unroll
        for (int q = 0; q < 4; q++) ca.u[q] = pA[q];
#pragma unroll
        for (int q = 0; q < 4; q++) cb.u[q] = pB[q];
#pragma unroll
        for (int c = 0; c < 16; c++) acc.h[c] = ca.h[c] * wnw2;
#pragma unroll
        for (int q = 0; q < 4; q++) cc4.u[q] = pC[q];
#pragma unroll
        for (int c = 0; c < 16; c++) acc.h[c] = cb.h[c] * wne2 + acc.h[c];
#pragma unroll
        for (int q = 0; q < 4; q++) cd.u[q] = pD[q];
#pragma unroll
        for (int c = 0; c < 16; c++) acc.h[c] = cc4.h[c] * wsw2 + acc.h[c];
#pragma unroll
        for (int c = 0; c < 16; c++) {
            acc.h[c] = cd.h[c] * wse2 + acc.h[c];
            acc.h[c] = __builtin_elementwise_max(acc.h[c], z2);   // relu, packed
        }

        // stage A-frags (swizzled, conflict-free); WAR vs prev view's reads is
        // safe: DS ops are in-order per wave.
#pragma unroll
        for (int q = 0; q < 4; q++)
            *(uint4*)(a2b + lane * 32 + (q ^ wsw0) * 8) = acc.u[q];
        wave_lds_sync();

        // layer 2 per tile: read A-frag, MFMA, relu+cvt into h2 [pt][ch]
#pragma unroll
        for (int T = 0; T < 4; T++) {
            half8_t a2 = *(const half8_t*)(a2b + (T*16 + m) * 32 + (g ^ rsw0) * 8);
            floatx4 c2 = __builtin_amdgcn_mfma_f32_16x16x32_f16(a2, w2frag, cb2, 0, 0, 0);
#pragma unroll
            for (int r = 0; r < 4; r++) {
                float hv = fmaxf(c2[r], 0.0f);
                h2b[(T*16 + g*4 + r) * 24 + m] = (_Float16)hv;
            }
        }
        wave_lds_sync();

        // layer 3: A = h2 rows (lane&15 = point-row), B = zero-padded W3, C = bias
        float msr = __builtin_amdgcn_rcpf((float)popc + 1e-8f);
        unsigned int balT[4];
        balT[0] = (unsigned int)bal;
        balT[1] = (unsigned int)(bal >> 16);
        balT[2] = (unsigned int)(bal >> 32);
        balT[3] = (unsigned int)(bal >> 48);
#pragma unroll
        for (int T = 0; T < 4; T++) {
            half8_t a3 = *(const half8_t*)(h2b + (T*16 + m) * 24 + (g & 1) * 8);
            floatx4 c3 = __builtin_amdgcn_mfma_f32_16x16x32_f16(a3, w3frag, cb3, 0, 0, 0);
#pragma unroll
            for (int r = 0; r < 4; r++) {
                float w = ((balT[T] >> (g*4 + r)) & 1u) ? msr : 0.0f;
                float val = c3[r];
                float t1 = w * val;
                S16[T*4+r] += w;
                M1[T*4+r]  += t1;
                Msq[T*4+r]  = fmaf(t1, val, Msq[T*4+r]);
            }
        }
    }

    // epilogue: lane (m<8, g) stores points T*16+g*4..+3, mean plane m, var plane m+8
    if (m < C3) {
        size_t base = (size_t)col * 64;
#pragma unroll
        for (int T = 0; T < 4; T++) {
            float4 mn, vr;
            mn.x = M1[T*4+0]; mn.y = M1[T*4+1]; mn.z = M1[T*4+2]; mn.w = M1[T*4+3];
            vr.x = fmaf(mn.x*mn.x, S16[T*4+0]-2.0f, Msq[T*4+0]);
            vr.y = fmaf(mn.y*mn.y, S16[T*4+1]-2.0f, Msq[T*4+1]);
            vr.z = fmaf(mn.z*mn.z, S16[T*4+2]-2.0f, Msq[T*4+2]);
            vr.w = fmaf(mn.w*mn.w, S16[T*4+3]-2.0f, Msq[T*4+3]);
            size_t ob = base + T*16 + g*4;
            *(float4*)(out + (size_t)m       * 262144 + ob) = mn;
            *(float4*)(out + (size_t)(m + 8) * 262144 + ob) = vr;
        }
    }
}

// ---- launch ----
extern "C" void kernel_launch(void* const* d_in, const int* in_sizes, int n_in,
                              void* d_out, int out_size, void* d_ws, size_t ws_size,
                              hipStream_t stream) {
    const float* feats = (const float*)d_in[0];
    const float* poses = (const float*)d_in[1];
    const float* Ks    = (const float*)d_in[2];
    const float* bbox  = (const float*)d_in[3];
    const int*   img_h = (const int*)d_in[4];
    const int*   img_w = (const int*)d_in[5];
    const float* W1    = (const float*)d_in[6];
    const float* b1    = (const float*)d_in[7];
    const float* W2    = (const float*)d_in[8];
    const float* b2    = (const float*)d_in[9];
    const float* W3    = (const float*)d_in[10];
    const float* b3    = (const float*)d_in[11];
    float* out = (float*)d_out;
    float* ws  = (float*)d_ws;

    float*     mats = ws;                        // 96 floats (pad to 128)
    _Float16*  w2f  = (_Float16*)(ws + 128);     // 512 halves (256 floats)
    _Float16*  w3f  = (_Float16*)(ws + 384);     // 512 halves
    float*     b2f  = ws + 640;                  // 64
    float*     b3f  = ws + 704;                  // 64
    uint4*     Gh   = (uint4*)(ws + 768);        // 8*16384*64 B = 8.39 MB, 16B-aligned

    hipLaunchKernelGGL(k_g, dim3(513), dim3(256), 0, stream,
                       feats, W1, b1, Gh, Ks, poses, img_h, img_w,
                       W2, b2, W3, b3, mats, w2f, w3f, b2f, b3f);
    hipLaunchKernelGGL(k_main, dim3(1024), dim3(256), 0, stream,
                       Gh, mats, bbox, w2f, w3f, b2f, b3f, out);
}